// Round 5
// baseline (897.780 us; speedup 1.0000x reference)
//
#include <hip/hip_runtime.h>

#define NROWS 16384
#define DIM   1024
#define QSCALE 32.0f            // fp4 pre-scale 2^5
#define E8M0S  0x7A7A7A7Au      // 122 -> 2^-5 in every byte (both operands)

typedef int    v4i    __attribute__((ext_vector_type(4)));
typedef int    v8i    __attribute__((ext_vector_type(8)));
typedef float  f32x16 __attribute__((ext_vector_type(16)));

__device__ __forceinline__ void glds16(const void* g, void* l) {
    __builtin_amdgcn_global_load_lds(
        (const __attribute__((address_space(1))) void*)g,
        (__attribute__((address_space(3))) void*)l,
        16, 0, 0);
}

__device__ __forceinline__ float fexp2(float x) {
#if __has_builtin(__builtin_amdgcn_exp2f)
    return __builtin_amdgcn_exp2f(x);
#else
    return exp2f(x);
#endif
}
__device__ __forceinline__ float flog2(float x) {
#if __has_builtin(__builtin_amdgcn_logf)
    return __builtin_amdgcn_logf(x);
#else
    return log2f(x);
#endif
}

// fp4 e2m1 round-to-nearest encode of y (|y| clipped to 6).
__device__ __forceinline__ unsigned fp4_nib(float y) {
    unsigned s = (__float_as_uint(y) >> 31) << 3;
    float a = fminf(fabsf(y), 6.0f);
    unsigned c = (unsigned)(a >= 0.25f) + (unsigned)(a >= 0.75f) +
                 (unsigned)(a >= 1.25f) + (unsigned)(a >= 1.75f) +
                 (unsigned)(a >= 2.5f)  + (unsigned)(a >= 3.5f)  +
                 (unsigned)(a >= 5.0f);
    return c | s;
}

// Wave-per-row, grid-stride. Lane-interleaved float4 loads: every load
// instruction is a fully-coalesced 1KB wave transaction.
__global__ __launch_bounds__(256) void norm_fused(
    const float* __restrict__ img,
    const float* __restrict__ txt,
    unsigned char* __restrict__ imgQ,   // [NROWS][512] packed fp4
    unsigned char* __restrict__ txtQ,
    const float* __restrict__ lscale,
    const float* __restrict__ lbias,
    float* __restrict__ diagPart) {
    const int t    = threadIdx.x;
    const int lane = t & 63;
    const int wave = t >> 6;
    const int gw   = blockIdx.x * 4 + wave;   // 8192 waves total
    const float sc   = __expf(lscale[0]);
    const float bias = lbias[0];

    for (int row = gw; row < NROWS; row += 8192) {
        const float4* pi = (const float4*)(img + (size_t)row * DIM);
        const float4* pt = (const float4*)(txt + (size_t)row * DIM);
        float4 vi[4], vt[4];
        float ssi = 0.0f, sst = 0.0f, dot = 0.0f;
        #pragma unroll
        for (int j = 0; j < 4; ++j) {
            vi[j] = pi[lane + 64 * j];
            vt[j] = pt[lane + 64 * j];
            ssi += vi[j].x*vi[j].x + vi[j].y*vi[j].y + vi[j].z*vi[j].z + vi[j].w*vi[j].w;
            sst += vt[j].x*vt[j].x + vt[j].y*vt[j].y + vt[j].z*vt[j].z + vt[j].w*vt[j].w;
            dot += vi[j].x*vt[j].x + vi[j].y*vt[j].y + vi[j].z*vt[j].z + vi[j].w*vt[j].w;
        }
        #pragma unroll
        for (int off = 1; off < 64; off <<= 1) {
            ssi += __shfl_xor(ssi, off, 64);
            sst += __shfl_xor(sst, off, 64);
            dot += __shfl_xor(dot, off, 64);
        }
        const float ii = 1.0f / fmaxf(sqrtf(ssi), 1e-12f);
        const float it = 1.0f / fmaxf(sqrtf(sst), 1e-12f);
        if (lane == 0) diagPart[row] = -fmaf(sc, dot * ii * it, bias);

        const float qi = ii * QSCALE, qt = it * QSCALE;
        ushort* oi = (ushort*)(imgQ + (size_t)row * 512);
        ushort* ot = (ushort*)(txtQ + (size_t)row * 512);
        #pragma unroll
        for (int j = 0; j < 4; ++j) {
            unsigned p = fp4_nib(vi[j].x * qi)        | (fp4_nib(vi[j].y * qi) << 4) |
                         (fp4_nib(vi[j].z * qi) << 8) | (fp4_nib(vi[j].w * qi) << 12);
            unsigned q = fp4_nib(vt[j].x * qt)        | (fp4_nib(vt[j].y * qt) << 4) |
                         (fp4_nib(vt[j].z * qt) << 8) | (fp4_nib(vt[j].w * qt) << 12);
            oi[lane + 64 * j] = (ushort)p;
            ot[lane + 64 * j] = (ushort)q;
        }
    }
}

// MX-fp4 GEMM, PERSISTENT: grid 256 (1 block/CU by 128KB LDS), each block
// owns 16 output tiles of 256x256 (XCD-banded: bcol band (blk&7)*8).
// 512 threads (8 waves as 2x4), BK=256 elems, 4 K-tiles/tile, dbuf LDS.
//
// R5 changes vs R4 (which was schedule-invariant at ~33% MfmaUtil):
//  (a) staging DMA SPREAD: 2 glds16 per ks-slice (A pairs slices 0-1,
//      B pairs slices 2-3), issued after the slice's lgkm wait -> DMA
//      streams during MFMA bursts instead of head-blocking the tile's
//      first ds_reads (the convoy all of R2/R3/R4 shared).
//  (b) persistent tile loop: during (tile,k=3) staging targets
//      (tile+1,k=0); the epilogue's ~2500cy of exp2/log VALU runs with
//      that DMA in flight; 15/16 cold prologues eliminated. Loss terms
//      accumulate in a register across tiles; ONE LDS reduce per block.
// Race ledger: staging writes buf[cur^1], whose readers drained at the
// previous gate (slice3 lgkm(0) precedes it); gate = vmcnt(0)+s_barrier
// at k-end (k<3) or after epilogue (k==3). lgkm counts only ds_reads.
// LDS slot s of row r holds global chunk s ^ (r&7) ^ ((r>>4)&1) (measured
// zero-conflict scatter swizzle, unchanged).
__global__ __launch_bounds__(512, 2) void siglip_gemm(
    const unsigned char* __restrict__ A,
    const unsigned char* __restrict__ B,
    const float* __restrict__ lscale,
    const float* __restrict__ lbias,
    float* __restrict__ gemmPart)
{
    __shared__ unsigned char sA[2][256 * 128];  // 2 x 32 KB
    __shared__ unsigned char sB[2][256 * 128];  // 2 x 32 KB
    __shared__ float wred[8];

    const int t    = threadIdx.x;
    const int lane = t & 63;
    const int wave = t >> 6;        // 0..7
    const int wr   = wave >> 2;     // 0..1 : A half (128 rows)
    const int wc   = wave & 3;      // 0..3 : B quarter (64 cols)
    const int r31  = lane & 31;
    const int h    = lane >> 5;     // k-half (32-elem MX block)
    const int xr   = (r31 & 7) ^ ((r31 >> 4) & 1);  // scatter row swizzle

    const int blk = blockIdx.x;     // 0..255, 1 block per CU

    // Staging: glds16 = 1KB = 8 rows x 128B. lane -> (srow=l>>3, slot=l&7).
    // Wave w stages A rows [w*32, w*32+32) = 4 slabs; same for B.
    const int srow = lane >> 3;
    const int c0   = (lane & 7) ^ srow;
    const int d01  = (c0 & 1) ? -16 : 16;   // toggle chunk bit0 when (row>>4)&1
    const int off0 = (wave * 32 + srow) * 512 + c0 * 16;

    int rbA[4], rbB[2];
    #pragma unroll
    for (int i = 0; i < 4; ++i) rbA[i] = (wr * 128 + i * 32 + r31) * 128;
    #pragma unroll
    for (int i = 0; i < 2; ++i) rbB[i] = (wc * 64 + i * 32 + r31) * 128;

    f32x16 acc[4][2] = {};

    const float l2e   = 1.44269504088896341f;
    const float aCo   = __expf(lscale[0]) * l2e;
    const float bCo   = lbias[0] * l2e;
    float local = 0.0f;             // loss accumulator across all 16 tiles

    // ---- one-time prologue: stage (tile0, k0) into buffer 0 ----
    {
        const unsigned char* a0 = A + (size_t)((blk >> 3) * 2) * 131072 + off0;
        const unsigned char* b0 = B + (size_t)((blk & 7) * 8) * 131072 + off0;
        char* la = ((char*)sA[0]) + wave * 4096;
        char* lb = ((char*)sB[0]) + wave * 4096;
        glds16(a0,                la);
        glds16(a0 + 4096,         la + 1024);
        glds16(a0 + 8192  + d01,  la + 2048);
        glds16(a0 + 12288 + d01,  la + 3072);
        glds16(b0,                lb);
        glds16(b0 + 4096,         lb + 1024);
        glds16(b0 + 8192  + d01,  lb + 2048);
        glds16(b0 + 12288 + d01,  lb + 3072);
        asm volatile("s_waitcnt vmcnt(0)" ::: "memory");
    }
    __builtin_amdgcn_s_barrier();

    for (int tile = 0; tile < 16; ++tile) {
        // this tile / next tile coordinates (next clamped into range; its
        // pointers are computed but only dereferenced when tile < 15)
        const int browC = (blk >> 3) * 2 + (tile >> 3);
        const int bcolC = (blk & 7) * 8 + (tile & 7);
        const int tN    = (tile + 1) & 15;
        const int browN = (blk >> 3) * 2 + (tN >> 3);
        const int bcolN = (blk & 7) * 8 + (tN & 7);

        const unsigned char* aCur = A + (size_t)browC * 131072 + off0;
        const unsigned char* bCur = B + (size_t)bcolC * 131072 + off0;
        const unsigned char* aNxt = A + (size_t)browN * 131072 + off0;
        const unsigned char* bNxt = B + (size_t)bcolN * 131072 + off0;

        #pragma unroll
        for (int k = 0; k < 4; ++k) {
            const int cur = k & 1;
            // staging target for this K-step (issued spread across slices)
            const unsigned char* gA = (k < 3 ? aCur + (k + 1) * 128 : aNxt);
            const unsigned char* gB = (k < 3 ? bCur + (k + 1) * 128 : bNxt);
            const bool doStage = (k < 3) || (tile < 15);
            char* laN = ((char*)sA[cur ^ 1]) + wave * 4096;
            char* lbN = ((char*)sB[cur ^ 1]) + wave * 4096;

            // ---- slice pipeline: read ks+1 under MFMA of ks ----
            v4i pa[2][4], pb[2][2];
            {
                const int s0 = (h ^ xr) * 16;
                #pragma unroll
                for (int i = 0; i < 4; ++i)
                    pa[0][i] = *(const v4i*)(sA[cur] + rbA[i] + s0);
                #pragma unroll
                for (int n = 0; n < 2; ++n)
                    pb[0][n] = *(const v4i*)(sB[cur] + rbB[n] + s0);
            }

            #pragma unroll
            for (int ks = 0; ks < 4; ++ks) {
                const int pc = ks & 1, pn = pc ^ 1;
                if (ks < 3) {
                    const int s1 = (((ks + 1) * 2 + h) ^ xr) * 16;
                    #pragma unroll
                    for (int i = 0; i < 4; ++i)
                        pa[pn][i] = *(const v4i*)(sA[cur] + rbA[i] + s1);
                    #pragma unroll
                    for (int n = 0; n < 2; ++n)
                        pb[pn][n] = *(const v4i*)(sB[cur] + rbB[n] + s1);
                    asm volatile("s_waitcnt lgkmcnt(6)" ::: "memory");
                } else {
                    asm volatile("s_waitcnt lgkmcnt(0)" ::: "memory");
                }
                __builtin_amdgcn_sched_barrier(0);   // rule 18

                // spread staging: 2 glds in this slice's MFMA shadow
                if (doStage) {
                    if (ks == 0) {
                        glds16(gA,               laN);
                        glds16(gA + 4096,        laN + 1024);
                    } else if (ks == 1) {
                        glds16(gA + 8192  + d01, laN + 2048);
                        glds16(gA + 12288 + d01, laN + 3072);
                    } else if (ks == 2) {
                        glds16(gB,               lbN);
                        glds16(gB + 4096,        lbN + 1024);
                    } else {
                        glds16(gB + 8192  + d01, lbN + 2048);
                        glds16(gB + 12288 + d01, lbN + 3072);
                    }
                }
                __builtin_amdgcn_sched_barrier(0);

                v8i a8[4], b8[2];
                #pragma unroll
                for (int i = 0; i < 4; ++i)
                    a8[i] = __builtin_shufflevector(pa[pc][i], pa[pc][i],
                                                    0, 1, 2, 3, -1, -1, -1, -1);
                #pragma unroll
                for (int n = 0; n < 2; ++n)
                    b8[n] = __builtin_shufflevector(pb[pc][n], pb[pc][n],
                                                    0, 1, 2, 3, -1, -1, -1, -1);

                __builtin_amdgcn_s_setprio(1);
                #pragma unroll
                for (int mi = 0; mi < 4; ++mi)
                    #pragma unroll
                    for (int ni = 0; ni < 2; ++ni)
                        acc[mi][ni] = __builtin_amdgcn_mfma_scale_f32_32x32x64_f8f6f4(
                            a8[mi], b8[ni], acc[mi][ni],
                            4, 4,                     // cbsz=fp4, blgp=fp4
                            0, (int)E8M0S,
                            0, (int)E8M0S);
                __builtin_amdgcn_s_setprio(0);
            }

            // ---- K-step gate (k==3's gate deferred past the epilogue) ----
            if (k < 3) {
                asm volatile("s_waitcnt vmcnt(0)" ::: "memory");
                __builtin_amdgcn_sched_barrier(0);
                __builtin_amdgcn_s_barrier();
            }
        }

        // ---- epilogue: softplus over this tile's acc (DMA in flight) ----
        #pragma unroll
        for (int mi = 0; mi < 4; ++mi)
            #pragma unroll
            for (int ni = 0; ni < 2; ++ni) {
                #pragma unroll
                for (int r = 0; r < 16; r += 4) {
                    float e0 = fexp2(fmaf(aCo, acc[mi][ni][r + 0], bCo));
                    float e1 = fexp2(fmaf(aCo, acc[mi][ni][r + 1], bCo));
                    float e2 = fexp2(fmaf(aCo, acc[mi][ni][r + 2], bCo));
                    float e3 = fexp2(fmaf(aCo, acc[mi][ni][r + 3], bCo));
                    float p  = ((1.0f + e0) * (1.0f + e1)) *
                               ((1.0f + e2) * (1.0f + e3));
                    local += flog2(p);
                }
                acc[mi][ni] = (f32x16)0.0f;   // reset for next tile
            }

        // ---- tile gate: staged (next tile, k0) visible to all waves ----
        asm volatile("s_waitcnt vmcnt(0)" ::: "memory");
        __builtin_amdgcn_sched_barrier(0);
        __builtin_amdgcn_s_barrier();
    }

    // ---- one reduce per block ----
    #pragma unroll
    for (int off = 32; off > 0; off >>= 1) local += __shfl_down(local, off, 64);
    if (lane == 0) wred[wave] = local;
    __syncthreads();
    if (t == 0) {
        float tot = 0.0f;
        #pragma unroll
        for (int i = 0; i < 8; ++i) tot += wred[i];
        gemmPart[blk] = tot * 0.69314718055994531f;
    }
}

// Sum 16640 partials (diagPart 16384 ++ gemmPart 256, contiguous) -> loss.
__global__ __launch_bounds__(1024) void finalize_kernel(
    const float* __restrict__ parts, float* __restrict__ out) {
    __shared__ float wr[16];
    const int t    = threadIdx.x;
    const int lane = t & 63;
    const int wave = t >> 6;
    const float4* p4 = (const float4*)parts;   // 4160 float4
    float s = 0.0f;
    for (int i = t; i < 4160; i += 1024) {
        float4 v = p4[i];
        s += v.x + v.y + v.z + v.w;
    }
    #pragma unroll
    for (int off = 32; off > 0; off >>= 1) s += __shfl_down(s, off, 64);
    if (lane == 0) wr[wave] = s;
    __syncthreads();
    if (t == 0) {
        float tot = 0.0f;
        #pragma unroll
        for (int i = 0; i < 16; ++i) tot += wr[i];
        out[0] = tot / 268435456.0f;   // / N^2
    }
}

extern "C" void kernel_launch(void* const* d_in, const int* in_sizes, int n_in,
                              void* d_out, int out_size, void* d_ws, size_t ws_size,
                              hipStream_t stream) {
    const float* img    = (const float*)d_in[0];
    const float* txt    = (const float*)d_in[1];
    const float* lscale = (const float*)d_in[2];
    const float* lbias  = (const float*)d_in[3];
    float* out = (float*)d_out;

    char* ws = (char*)d_ws;
    unsigned char* imgQ = (unsigned char*)ws;                          // 8 MB
    unsigned char* txtQ = (unsigned char*)(ws + (size_t)NROWS * 512);  // 8 MB
    float* parts   = (float*)(ws + (size_t)2 * NROWS * 512);           // 16640 floats
    float* diagPart = parts;
    float* gemmPart = parts + NROWS;

    norm_fused<<<2048, 256, 0, stream>>>(img, txt, imgQ, txtQ, lscale, lbias, diagPart);
    siglip_gemm<<<256, 512, 0, stream>>>(imgQ, txtQ, lscale, lbias, gemmPart);
    finalize_kernel<<<1, 1024, 0, stream>>>(parts, out);
}

// Round 6
// 330.240 us; speedup vs baseline: 2.7186x; 2.7186x over previous
//
#include <hip/hip_runtime.h>

#define NROWS 16384
#define DIM   1024
#define QSCALE 32.0f            // fp4 pre-scale 2^5
#define E8M0S  0x7A7A7A7Au      // 122 -> 2^-5 in every byte (both operands)

typedef int    v4i    __attribute__((ext_vector_type(4)));
typedef int    v8i    __attribute__((ext_vector_type(8)));
typedef float  f32x16 __attribute__((ext_vector_type(16)));

__device__ __forceinline__ void glds16(const void* g, void* l) {
    __builtin_amdgcn_global_load_lds(
        (const __attribute__((address_space(1))) void*)g,
        (__attribute__((address_space(3))) void*)l,
        16, 0, 0);
}

__device__ __forceinline__ float fexp2(float x) {
#if __has_builtin(__builtin_amdgcn_exp2f)
    return __builtin_amdgcn_exp2f(x);
#else
    return exp2f(x);
#endif
}
__device__ __forceinline__ float flog2(float x) {
#if __has_builtin(__builtin_amdgcn_logf)
    return __builtin_amdgcn_logf(x);
#else
    return log2f(x);
#endif
}

// fp4 e2m1 round-to-nearest encode of y (|y| clipped to 6).
__device__ __forceinline__ unsigned fp4_nib(float y) {
    unsigned s = (__float_as_uint(y) >> 31) << 3;
    float a = fminf(fabsf(y), 6.0f);
    unsigned c = (unsigned)(a >= 0.25f) + (unsigned)(a >= 0.75f) +
                 (unsigned)(a >= 1.25f) + (unsigned)(a >= 1.75f) +
                 (unsigned)(a >= 2.5f)  + (unsigned)(a >= 3.5f)  +
                 (unsigned)(a >= 5.0f);
    return c | s;
}

// Wave-per-row, grid-stride. Lane-interleaved float4 loads: every load
// instruction is a fully-coalesced 1KB wave transaction.
__global__ __launch_bounds__(256) void norm_fused(
    const float* __restrict__ img,
    const float* __restrict__ txt,
    unsigned char* __restrict__ imgQ,   // [NROWS][512] packed fp4
    unsigned char* __restrict__ txtQ,
    const float* __restrict__ lscale,
    const float* __restrict__ lbias,
    float* __restrict__ diagPart) {
    const int t    = threadIdx.x;
    const int lane = t & 63;
    const int wave = t >> 6;
    const int gw   = blockIdx.x * 4 + wave;   // 8192 waves total
    const float sc   = __expf(lscale[0]);
    const float bias = lbias[0];

    for (int row = gw; row < NROWS; row += 8192) {
        const float4* pi = (const float4*)(img + (size_t)row * DIM);
        const float4* pt = (const float4*)(txt + (size_t)row * DIM);
        float4 vi[4], vt[4];
        float ssi = 0.0f, sst = 0.0f, dot = 0.0f;
        #pragma unroll
        for (int j = 0; j < 4; ++j) {
            vi[j] = pi[lane + 64 * j];
            vt[j] = pt[lane + 64 * j];
            ssi += vi[j].x*vi[j].x + vi[j].y*vi[j].y + vi[j].z*vi[j].z + vi[j].w*vi[j].w;
            sst += vt[j].x*vt[j].x + vt[j].y*vt[j].y + vt[j].z*vt[j].z + vt[j].w*vt[j].w;
            dot += vi[j].x*vt[j].x + vi[j].y*vt[j].y + vi[j].z*vt[j].z + vi[j].w*vt[j].w;
        }
        #pragma unroll
        for (int off = 1; off < 64; off <<= 1) {
            ssi += __shfl_xor(ssi, off, 64);
            sst += __shfl_xor(sst, off, 64);
            dot += __shfl_xor(dot, off, 64);
        }
        const float ii = 1.0f / fmaxf(sqrtf(ssi), 1e-12f);
        const float it = 1.0f / fmaxf(sqrtf(sst), 1e-12f);
        if (lane == 0) diagPart[row] = -fmaf(sc, dot * ii * it, bias);

        const float qi = ii * QSCALE, qt = it * QSCALE;
        ushort* oi = (ushort*)(imgQ + (size_t)row * 512);
        ushort* ot = (ushort*)(txtQ + (size_t)row * 512);
        #pragma unroll
        for (int j = 0; j < 4; ++j) {
            unsigned p = fp4_nib(vi[j].x * qi)        | (fp4_nib(vi[j].y * qi) << 4) |
                         (fp4_nib(vi[j].z * qi) << 8) | (fp4_nib(vi[j].w * qi) << 12);
            unsigned q = fp4_nib(vt[j].x * qt)        | (fp4_nib(vt[j].y * qt) << 4) |
                         (fp4_nib(vt[j].z * qt) << 8) | (fp4_nib(vt[j].w * qt) << 12);
            oi[lane + 64 * j] = (ushort)p;
            ot[lane + 64 * j] = (ushort)q;
        }
    }
}

// MX-fp4 GEMM, 256x256 tile, 512 threads (8 waves as 2x4), BK=256 elems
// (128B rows), 4 K-tiles, SINGLE-buffer LDS (64 KB).
//
// R6: R5's counters exposed that R2-R4's "dbuf" 128.5KB LDS only fit
// 1 block/CU = 2 waves/SIMD (Occupancy 22%) — no wave-level slack, so
// LDS-read pipe and matrix pipe SERIALIZED (sum, not max) regardless of
// intra-wave schedule (R2/R3/R4 all ~185-194us, MfmaUtil ~32%).
// Fix: single 64KB buffer -> 2 blocks/CU = 16 waves/CU = 4 waves/SIMD.
// The exposed per-K-tile stage-wait (single buffer) is masked by the
// SIBLING BLOCK's compute; intra-wave slice pipeline (counted lgkmcnt)
// retained from R4.
// Race ledger (single buffer): reads of tile k happen between the
// post-stage barrier and the post-compute barrier (each wave's ks=3
// lgkmcnt(0) retires its reads before that barrier); stage k+1 DMA
// issues only after the post-compute barrier; vmcnt(0)+barrier before
// the next compute makes the DMA visible to all waves.
// LDS slot s of row r holds global chunk s ^ (r&7) ^ ((r>>4)&1) (measured
// zero-conflict scatter swizzle, unchanged).
__global__ __launch_bounds__(512, 2) void siglip_gemm(
    const unsigned char* __restrict__ A,
    const unsigned char* __restrict__ B,
    const float* __restrict__ lscale,
    const float* __restrict__ lbias,
    float* __restrict__ gemmPart)
{
    __shared__ unsigned char sA[256 * 128];  // 32 KB
    __shared__ unsigned char sB[256 * 128];  // 32 KB
    __shared__ float wred[8];

    const int t    = threadIdx.x;
    const int lane = t & 63;
    const int wave = t >> 6;        // 0..7
    const int wr   = wave >> 2;     // 0..1 : A half (128 rows)
    const int wc   = wave & 3;      // 0..3 : B quarter (64 cols)
    const int r31  = lane & 31;
    const int h    = lane >> 5;     // k-half (32-elem MX block)
    const int xr   = (r31 & 7) ^ ((r31 >> 4) & 1);  // scatter row swizzle

    // XCD-bijective map (T1): each XCD keeps an 8-bcol B band (1 MB)
    // resident in its private L2 for the whole kernel; A streams through.
    // Measured R3: FETCH 135 -> 37 MB. 4096 blocks = 8 xcd x 512 lb.
    const int b    = blockIdx.x;
    const int xcd  = b & 7;
    const int lb   = b >> 3;          // 0..511
    const int bcol = xcd * 8 + (lb & 7);   // 0..63
    const int brow = lb >> 3;              // 0..63

    const size_t aBase = (size_t)brow * 256;
    const size_t bBase = (size_t)bcol * 256;

    // Staging: glds16 = 1KB = 8 rows x 128B. lane -> (srow=l>>3, slot=l&7).
    // Wave w stages A rows [w*32, w*32+32) = 4 slabs; same for B.
    const int srow = lane >> 3;
    const int c0   = (lane & 7) ^ srow;
    const int d01  = (c0 & 1) ? -16 : 16;   // toggle chunk bit0 when (row>>4)&1

    const unsigned char* aP = A + (size_t)(aBase + wave * 32 + srow) * 512 + c0 * 16;
    const unsigned char* bP = B + (size_t)(bBase + wave * 32 + srow) * 512 + c0 * 16;
    char* la = ((char*)sA) + wave * 4096;
    char* lbp = ((char*)sB) + wave * 4096;

    int rbA[4], rbB[2];
    #pragma unroll
    for (int i = 0; i < 4; ++i) rbA[i] = (wr * 128 + i * 32 + r31) * 128;
    #pragma unroll
    for (int i = 0; i < 2; ++i) rbB[i] = (wc * 64 + i * 32 + r31) * 128;

    f32x16 acc[4][2] = {};

    // ---- prologue: stage K-tile 0 ----
    #pragma unroll
    for (int j = 0; j < 4; ++j) {
        const int tog = ((j >> 1) & 1) ? d01 : 0;   // bit4 of row = (j>>1)&1
        glds16(aP + j * 8 * 512 + tog, la + j * 1024);
        glds16(bP + j * 8 * 512 + tog, lbp + j * 1024);
    }
    asm volatile("s_waitcnt vmcnt(0)" ::: "memory");
    __builtin_amdgcn_sched_barrier(0);
    __builtin_amdgcn_s_barrier();

    #pragma unroll
    for (int k = 0; k < 4; ++k) {
        // ---- compute tile k: slice pipeline (read ks+1 under MFMA ks) ----
        v4i pa[2][4], pb[2][2];     // two slice reg-sets; indices static
        {
            const int s0 = (h ^ xr) * 16;
            #pragma unroll
            for (int i = 0; i < 4; ++i)
                pa[0][i] = *(const v4i*)(sA + rbA[i] + s0);
            #pragma unroll
            for (int n = 0; n < 2; ++n)
                pb[0][n] = *(const v4i*)(sB + rbB[n] + s0);
        }

        #pragma unroll
        for (int ks = 0; ks < 4; ++ks) {
            const int pc = ks & 1, pn = pc ^ 1;
            if (ks < 3) {
                const int s1 = (((ks + 1) * 2 + h) ^ xr) * 16;
                #pragma unroll
                for (int i = 0; i < 4; ++i)
                    pa[pn][i] = *(const v4i*)(sA + rbA[i] + s1);
                #pragma unroll
                for (int n = 0; n < 2; ++n)
                    pb[pn][n] = *(const v4i*)(sB + rbB[n] + s1);
                asm volatile("s_waitcnt lgkmcnt(6)" ::: "memory");
            } else {
                asm volatile("s_waitcnt lgkmcnt(0)" ::: "memory");
            }
            __builtin_amdgcn_sched_barrier(0);   // rule 18: pin MFMA after wait

            v8i a8[4], b8[2];
            #pragma unroll
            for (int i = 0; i < 4; ++i)
                a8[i] = __builtin_shufflevector(pa[pc][i], pa[pc][i],
                                                0, 1, 2, 3, -1, -1, -1, -1);
            #pragma unroll
            for (int n = 0; n < 2; ++n)
                b8[n] = __builtin_shufflevector(pb[pc][n], pb[pc][n],
                                                0, 1, 2, 3, -1, -1, -1, -1);

            __builtin_amdgcn_s_setprio(1);
            #pragma unroll
            for (int mi = 0; mi < 4; ++mi)
                #pragma unroll
                for (int ni = 0; ni < 2; ++ni)
                    acc[mi][ni] = __builtin_amdgcn_mfma_scale_f32_32x32x64_f8f6f4(
                        a8[mi], b8[ni], acc[mi][ni],
                        4, 4,                     // cbsz=fp4(e2m1), blgp=fp4
                        0, (int)E8M0S,
                        0, (int)E8M0S);
            __builtin_amdgcn_s_setprio(0);
        }

        // ---- stage tile k+1 (single buffer: after reads drain) ----
        if (k < 3) {
            __builtin_amdgcn_s_barrier();        // all waves' reads retired
            const unsigned char* aN = aP + (k + 1) * 128;
            const unsigned char* bN = bP + (k + 1) * 128;
            #pragma unroll
            for (int j = 0; j < 4; ++j) {
                const int tog = ((j >> 1) & 1) ? d01 : 0;
                glds16(aN + j * 8 * 512 + tog, la + j * 1024);
                glds16(bN + j * 8 * 512 + tog, lbp + j * 1024);
            }
            asm volatile("s_waitcnt vmcnt(0)" ::: "memory");
            __builtin_amdgcn_sched_barrier(0);
            __builtin_amdgcn_s_barrier();        // staged data visible
        }
    }

    // Epilogue: softplus(z) over all elements (label=-1 form); diagonal fixed
    // by -z_ii. Group-of-4 log trick (t <= ~31, 4-term product < 2^125: safe).
    const float l2e   = 1.44269504088896341f;
    const float scale = __expf(lscale[0]);
    const float aCo   = scale * l2e;
    const float bCo   = lbias[0] * l2e;
    float local = 0.0f;
    #pragma unroll
    for (int mi = 0; mi < 4; ++mi)
        #pragma unroll
        for (int ni = 0; ni < 2; ++ni)
            #pragma unroll
            for (int r = 0; r < 16; r += 4) {
                float e0 = fexp2(fmaf(aCo, acc[mi][ni][r + 0], bCo));
                float e1 = fexp2(fmaf(aCo, acc[mi][ni][r + 1], bCo));
                float e2 = fexp2(fmaf(aCo, acc[mi][ni][r + 2], bCo));
                float e3 = fexp2(fmaf(aCo, acc[mi][ni][r + 3], bCo));
                float p  = ((1.0f + e0) * (1.0f + e1)) *
                           ((1.0f + e2) * (1.0f + e3));
                local += flog2(p);
            }

    #pragma unroll
    for (int off = 32; off > 0; off >>= 1) local += __shfl_down(local, off, 64);
    if (lane == 0) wred[wave] = local;
    __syncthreads();
    if (t == 0) {
        float tot = 0.0f;
        #pragma unroll
        for (int i = 0; i < 8; ++i) tot += wred[i];
        gemmPart[blockIdx.x] = tot * 0.69314718055994531f;
    }
}

// Sum 20480 partials (diagPart 16384 ++ gemmPart 4096, contiguous) -> loss.
__global__ __launch_bounds__(1024) void finalize_kernel(
    const float* __restrict__ parts, float* __restrict__ out) {
    __shared__ float wr[16];
    const int t    = threadIdx.x;
    const int lane = t & 63;
    const int wave = t >> 6;
    const float4* p4 = (const float4*)parts;   // 5120 float4
    float s = 0.0f;
    for (int i = t; i < 5120; i += 1024) {
        float4 v = p4[i];
        s += v.x + v.y + v.z + v.w;
    }
    #pragma unroll
    for (int off = 32; off > 0; off >>= 1) s += __shfl_down(s, off, 64);
    if (lane == 0) wr[wave] = s;
    __syncthreads();
    if (t == 0) {
        float tot = 0.0f;
        #pragma unroll
        for (int i = 0; i < 16; ++i) tot += wr[i];
        out[0] = tot / 268435456.0f;   // / N^2
    }
}

extern "C" void kernel_launch(void* const* d_in, const int* in_sizes, int n_in,
                              void* d_out, int out_size, void* d_ws, size_t ws_size,
                              hipStream_t stream) {
    const float* img    = (const float*)d_in[0];
    const float* txt    = (const float*)d_in[1];
    const float* lscale = (const float*)d_in[2];
    const float* lbias  = (const float*)d_in[3];
    float* out = (float*)d_out;

    char* ws = (char*)d_ws;
    unsigned char* imgQ = (unsigned char*)ws;                          // 8 MB
    unsigned char* txtQ = (unsigned char*)(ws + (size_t)NROWS * 512);  // 8 MB
    float* parts   = (float*)(ws + (size_t)2 * NROWS * 512);           // 20480 floats
    float* diagPart = parts;
    float* gemmPart = parts + NROWS;

    norm_fused<<<2048, 256, 0, stream>>>(img, txt, imgQ, txtQ, lscale, lbias, diagPart);
    siglip_gemm<<<dim3((NROWS / 256) * (NROWS / 256)), 512, 0, stream>>>(
        imgQ, txtQ, lscale, lbias, gemmPart);
    finalize_kernel<<<1, 1024, 0, stream>>>(parts, out);
}

// Round 7
// 322.284 us; speedup vs baseline: 2.7857x; 1.0247x over previous
//
#include <hip/hip_runtime.h>

#define NROWS 16384
#define DIM   1024
#define QSCALE 32.0f            // fp4 pre-scale 2^5
#define E8M0S  0x7A7A7A7Au      // 122 -> 2^-5 in every byte (both operands)

typedef int    v4i    __attribute__((ext_vector_type(4)));
typedef int    v8i    __attribute__((ext_vector_type(8)));
typedef float  f32x16 __attribute__((ext_vector_type(16)));

__device__ __forceinline__ void glds16(const void* g, void* l) {
    __builtin_amdgcn_global_load_lds(
        (const __attribute__((address_space(1))) void*)g,
        (__attribute__((address_space(3))) void*)l,
        16, 0, 0);
}

__device__ __forceinline__ float fexp2(float x) {
#if __has_builtin(__builtin_amdgcn_exp2f)
    return __builtin_amdgcn_exp2f(x);
#else
    return exp2f(x);
#endif
}
__device__ __forceinline__ float flog2(float x) {
#if __has_builtin(__builtin_amdgcn_logf)
    return __builtin_amdgcn_logf(x);
#else
    return log2f(x);
#endif
}

// fp4 e2m1 round-to-nearest encode of y (|y| clipped to 6).
__device__ __forceinline__ unsigned fp4_nib(float y) {
    unsigned s = (__float_as_uint(y) >> 31) << 3;
    float a = fminf(fabsf(y), 6.0f);
    unsigned c = (unsigned)(a >= 0.25f) + (unsigned)(a >= 0.75f) +
                 (unsigned)(a >= 1.25f) + (unsigned)(a >= 1.75f) +
                 (unsigned)(a >= 2.5f)  + (unsigned)(a >= 3.5f)  +
                 (unsigned)(a >= 5.0f);
    return c | s;
}

// Wave-per-row, grid-stride. Lane-interleaved float4 loads: every load
// instruction is a fully-coalesced 1KB wave transaction.
__global__ __launch_bounds__(256) void norm_fused(
    const float* __restrict__ img,
    const float* __restrict__ txt,
    unsigned char* __restrict__ imgQ,   // [NROWS][512] packed fp4
    unsigned char* __restrict__ txtQ,
    const float* __restrict__ lscale,
    const float* __restrict__ lbias,
    float* __restrict__ diagPart) {
    const int t    = threadIdx.x;
    const int lane = t & 63;
    const int wave = t >> 6;
    const int gw   = blockIdx.x * 4 + wave;   // 8192 waves total
    const float sc   = __expf(lscale[0]);
    const float bias = lbias[0];

    for (int row = gw; row < NROWS; row += 8192) {
        const float4* pi = (const float4*)(img + (size_t)row * DIM);
        const float4* pt = (const float4*)(txt + (size_t)row * DIM);
        float4 vi[4], vt[4];
        float ssi = 0.0f, sst = 0.0f, dot = 0.0f;
        #pragma unroll
        for (int j = 0; j < 4; ++j) {
            vi[j] = pi[lane + 64 * j];
            vt[j] = pt[lane + 64 * j];
            ssi += vi[j].x*vi[j].x + vi[j].y*vi[j].y + vi[j].z*vi[j].z + vi[j].w*vi[j].w;
            sst += vt[j].x*vt[j].x + vt[j].y*vt[j].y + vt[j].z*vt[j].z + vt[j].w*vt[j].w;
            dot += vi[j].x*vt[j].x + vi[j].y*vt[j].y + vi[j].z*vt[j].z + vi[j].w*vt[j].w;
        }
        #pragma unroll
        for (int off = 1; off < 64; off <<= 1) {
            ssi += __shfl_xor(ssi, off, 64);
            sst += __shfl_xor(sst, off, 64);
            dot += __shfl_xor(dot, off, 64);
        }
        const float ii = 1.0f / fmaxf(sqrtf(ssi), 1e-12f);
        const float it = 1.0f / fmaxf(sqrtf(sst), 1e-12f);
        if (lane == 0) diagPart[row] = -fmaf(sc, dot * ii * it, bias);

        const float qi = ii * QSCALE, qt = it * QSCALE;
        ushort* oi = (ushort*)(imgQ + (size_t)row * 512);
        ushort* ot = (ushort*)(txtQ + (size_t)row * 512);
        #pragma unroll
        for (int j = 0; j < 4; ++j) {
            unsigned p = fp4_nib(vi[j].x * qi)        | (fp4_nib(vi[j].y * qi) << 4) |
                         (fp4_nib(vi[j].z * qi) << 8) | (fp4_nib(vi[j].w * qi) << 12);
            unsigned q = fp4_nib(vt[j].x * qt)        | (fp4_nib(vt[j].y * qt) << 4) |
                         (fp4_nib(vt[j].z * qt) << 8) | (fp4_nib(vt[j].w * qt) << 12);
            oi[lane + 64 * j] = (ushort)p;
            ot[lane + 64 * j] = (ushort)q;
        }
    }
}

// MX-fp4 GEMM, 256x256 tile, 512 threads (8 waves as 2x4), BK=256 elems
// (128B rows), 4 K-tiles, double-buffered LDS (128 KB).
//
// R7: faithful m201 8-phase port. Occupancy is REGISTER-pinned at
// 2 waves/SIMD (acc=128 AGPR + ~100 VGPR = 228 regs/wave; R1-R6 all 22%)
// — same regime m201 runs in at 62% MfmaUtil, so the schedule must make
// the overlap, not TLP. Per K-tile, 4 phases:
//   {6 ds_read (slice p, buf[cur]) ; 2-3 glds16 (tile k+1 -> buf[cur^1],
//    spread 3/3/2/0) ; s_barrier ; lgkmcnt(0) ; sched_barrier(0) ;
//    setprio(1) ; 8 MFMA (slice p) ; setprio(0) ; s_barrier}
// Mechanism (m196/m218: the fine interleave IS the lever): after barrier
// #1, wave w's 6 reads clear the LDS queue at ~72*(w+1) cyc; early waves
// MFMA while the pipe serves later waves; SIMD-siblings hand off the
// matrix pipe -> phase ~860 cyc vs serial 1142 (66% ceiling; m201
// measured 62%). vmcnt(0) gate sits before phase-3's END barrier, ~2
// phases after the last glds issue -> effectively-free drain (m218:
// counted-not-drain0 is T3's entire gain).
// Race ledger: buf[cur^1] readers drained at tile k-1's phase-3
// lgkmcnt(0)+barrier, before tile k's glds issue; gate vmcnt(0)+barrier
// precedes tile k+1's phase-0 reads. lgkm counts only ds_reads.
// LDS slot s of row r holds global chunk s ^ (r&7) ^ ((r>>4)&1) (measured
// zero-conflict scatter swizzle, unchanged).
__global__ __launch_bounds__(512, 2) void siglip_gemm(
    const unsigned char* __restrict__ A,
    const unsigned char* __restrict__ B,
    const float* __restrict__ lscale,
    const float* __restrict__ lbias,
    float* __restrict__ gemmPart)
{
    __shared__ unsigned char sA[2][256 * 128];  // 2 x 32 KB
    __shared__ unsigned char sB[2][256 * 128];  // 2 x 32 KB
    __shared__ float wred[8];

    const int t    = threadIdx.x;
    const int lane = t & 63;
    const int wave = t >> 6;        // 0..7
    const int wr   = wave >> 2;     // 0..1 : A half (128 rows)
    const int wc   = wave & 3;      // 0..3 : B quarter (64 cols)
    const int r31  = lane & 31;
    const int h    = lane >> 5;     // k-half (32-elem MX block)
    const int xr   = (r31 & 7) ^ ((r31 >> 4) & 1);  // scatter row swizzle

    // XCD-bijective map (T1): each XCD keeps an 8-bcol B band (1 MB)
    // resident in its private L2 (measured R3: FETCH 135 -> 37 MB).
    const int b    = blockIdx.x;
    const int xcd  = b & 7;
    const int lb   = b >> 3;          // 0..511
    const int bcol = xcd * 8 + (lb & 7);   // 0..63
    const int brow = lb >> 3;              // 0..63

    const size_t aBase = (size_t)brow * 256;
    const size_t bBase = (size_t)bcol * 256;

    // Staging: glds16 = 1KB = 8 rows x 128B. lane -> (srow=l>>3, slot=l&7).
    // Wave w stages A rows [w*32, w*32+32) = 4 slabs; same for B.
    const int srow = lane >> 3;
    const int c0   = (lane & 7) ^ srow;
    const int d01  = (c0 & 1) ? -16 : 16;   // toggle chunk bit0 when (row>>4)&1

    const unsigned char* aP = A + (size_t)(aBase + wave * 32 + srow) * 512 + c0 * 16;
    const unsigned char* bP = B + (size_t)(bBase + wave * 32 + srow) * 512 + c0 * 16;

    int rbA[4], rbB[2];
    #pragma unroll
    for (int i = 0; i < 4; ++i) rbA[i] = (wr * 128 + i * 32 + r31) * 128;
    #pragma unroll
    for (int i = 0; i < 2; ++i) rbB[i] = (wc * 64 + i * 32 + r31) * 128;

    f32x16 acc[4][2] = {};

    // ---- prologue: stage K-tile 0 into buffer 0 ----
    {
        char* la = ((char*)sA[0]) + wave * 4096;
        char* lb_ = ((char*)sB[0]) + wave * 4096;
        #pragma unroll
        for (int j = 0; j < 4; ++j) {
            const int tog = ((j >> 1) & 1) ? d01 : 0;   // bit4 of row = (j>>1)&1
            glds16(aP + j * 8 * 512 + tog, la + j * 1024);
            glds16(bP + j * 8 * 512 + tog, lb_ + j * 1024);
        }
        asm volatile("s_waitcnt vmcnt(0)" ::: "memory");
    }
    __builtin_amdgcn_s_barrier();

    #pragma unroll
    for (int k = 0; k < 4; ++k) {
        const int cur = k & 1;      // compile-time under full unroll
        const bool stage = (k < 3);
        const unsigned char* aN = aP + (k + 1) * 128;
        const unsigned char* bN = bP + (k + 1) * 128;
        char* laN = ((char*)sA[cur ^ 1]) + wave * 4096;
        char* lbN = ((char*)sB[cur ^ 1]) + wave * 4096;

        #pragma unroll
        for (int p = 0; p < 4; ++p) {
            // ---- phase p: ds_read slice p of buf[cur] ----
            const int s = ((p * 2 + h) ^ xr) * 16;
            v4i av[4], bv[2];
            #pragma unroll
            for (int i = 0; i < 4; ++i)
                av[i] = *(const v4i*)(sA[cur] + rbA[i] + s);
            #pragma unroll
            for (int n = 0; n < 2; ++n)
                bv[n] = *(const v4i*)(sB[cur] + rbB[n] + s);

            // ---- spread staging: 3/3/2/0 glds for tile k+1 ----
            if (stage) {
                if (p == 0) {
                    glds16(aN,                laN);
                    glds16(aN + 4096,         laN + 1024);
                    glds16(aN + 8192  + d01,  laN + 2048);
                } else if (p == 1) {
                    glds16(aN + 12288 + d01,  laN + 3072);
                    glds16(bN,                lbN);
                    glds16(bN + 4096,         lbN + 1024);
                } else if (p == 2) {
                    glds16(bN + 8192  + d01,  lbN + 2048);
                    glds16(bN + 12288 + d01,  lbN + 3072);
                }
            }

            // ---- phase barrier #1: all waves' reads issued ----
            __builtin_amdgcn_s_barrier();
            asm volatile("s_waitcnt lgkmcnt(0)" ::: "memory");
            __builtin_amdgcn_sched_barrier(0);   // rule 18: pin MFMA after wait

            v8i a8[4], b8[2];
            #pragma unroll
            for (int i = 0; i < 4; ++i)
                a8[i] = __builtin_shufflevector(av[i], av[i],
                                                0, 1, 2, 3, -1, -1, -1, -1);
            #pragma unroll
            for (int n = 0; n < 2; ++n)
                b8[n] = __builtin_shufflevector(bv[n], bv[n],
                                                0, 1, 2, 3, -1, -1, -1, -1);

            __builtin_amdgcn_s_setprio(1);
            #pragma unroll
            for (int mi = 0; mi < 4; ++mi)
                #pragma unroll
                for (int ni = 0; ni < 2; ++ni)
                    acc[mi][ni] = __builtin_amdgcn_mfma_scale_f32_32x32x64_f8f6f4(
                        a8[mi], b8[ni], acc[mi][ni],
                        4, 4,                     // cbsz=fp4(e2m1), blgp=fp4
                        0, (int)E8M0S,
                        0, (int)E8M0S);
            __builtin_amdgcn_s_setprio(0);

            // ---- phase barrier #2 (phase 3: gate staging first) ----
            if (p == 3 && stage) {
                asm volatile("s_waitcnt vmcnt(0)" ::: "memory");
                __builtin_amdgcn_sched_barrier(0);
            }
            __builtin_amdgcn_s_barrier();
        }
    }

    // Epilogue: softplus(z) over all elements (label=-1 form); diagonal fixed
    // by -z_ii. Group-of-4 log trick (t <= ~31, 4-term product < 2^125: safe).
    const float l2e   = 1.44269504088896341f;
    const float scale = __expf(lscale[0]);
    const float aCo   = scale * l2e;
    const float bCo   = lbias[0] * l2e;
    float local = 0.0f;
    #pragma unroll
    for (int mi = 0; mi < 4; ++mi)
        #pragma unroll
        for (int ni = 0; ni < 2; ++ni)
            #pragma unroll
            for (int r = 0; r < 16; r += 4) {
                float e0 = fexp2(fmaf(aCo, acc[mi][ni][r + 0], bCo));
                float e1 = fexp2(fmaf(aCo, acc[mi][ni][r + 1], bCo));
                float e2 = fexp2(fmaf(aCo, acc[mi][ni][r + 2], bCo));
                float e3 = fexp2(fmaf(aCo, acc[mi][ni][r + 3], bCo));
                float p  = ((1.0f + e0) * (1.0f + e1)) *
                           ((1.0f + e2) * (1.0f + e3));
                local += flog2(p);
            }

    #pragma unroll
    for (int off = 32; off > 0; off >>= 1) local += __shfl_down(local, off, 64);
    if (lane == 0) wred[wave] = local;
    __syncthreads();
    if (t == 0) {
        float tot = 0.0f;
        #pragma unroll
        for (int i = 0; i < 8; ++i) tot += wred[i];
        gemmPart[blockIdx.x] = tot * 0.69314718055994531f;
    }
}

// Sum 20480 partials (diagPart 16384 ++ gemmPart 4096, contiguous) -> loss.
__global__ __launch_bounds__(1024) void finalize_kernel(
    const float* __restrict__ parts, float* __restrict__ out) {
    __shared__ float wr[16];
    const int t    = threadIdx.x;
    const int lane = t & 63;
    const int wave = t >> 6;
    const float4* p4 = (const float4*)parts;   // 5120 float4
    float s = 0.0f;
    for (int i = t; i < 5120; i += 1024) {
        float4 v = p4[i];
        s += v.x + v.y + v.z + v.w;
    }
    #pragma unroll
    for (int off = 32; off > 0; off >>= 1) s += __shfl_down(s, off, 64);
    if (lane == 0) wr[wave] = s;
    __syncthreads();
    if (t == 0) {
        float tot = 0.0f;
        #pragma unroll
        for (int i = 0; i < 16; ++i) tot += wr[i];
        out[0] = tot / 268435456.0f;   // / N^2
    }
}

extern "C" void kernel_launch(void* const* d_in, const int* in_sizes, int n_in,
                              void* d_out, int out_size, void* d_ws, size_t ws_size,
                              hipStream_t stream) {
    const float* img    = (const float*)d_in[0];
    const float* txt    = (const float*)d_in[1];
    const float* lscale = (const float*)d_in[2];
    const float* lbias  = (const float*)d_in[3];
    float* out = (float*)d_out;

    char* ws = (char*)d_ws;
    unsigned char* imgQ = (unsigned char*)ws;                          // 8 MB
    unsigned char* txtQ = (unsigned char*)(ws + (size_t)NROWS * 512);  // 8 MB
    float* parts   = (float*)(ws + (size_t)2 * NROWS * 512);           // 20480 floats
    float* diagPart = parts;
    float* gemmPart = parts + NROWS;

    norm_fused<<<2048, 256, 0, stream>>>(img, txt, imgQ, txtQ, lscale, lbias, diagPart);
    siglip_gemm<<<dim3((NROWS / 256) * (NROWS / 256)), 512, 0, stream>>>(
        imgQ, txtQ, lscale, lbias, gemmPart);
    finalize_kernel<<<1, 1024, 0, stream>>>(parts, out);
}

// Round 8
// 310.216 us; speedup vs baseline: 2.8940x; 1.0389x over previous
//
#include <hip/hip_runtime.h>

#define NROWS 16384
#define DIM   1024
#define QSCALE 32.0f            // fp4 pre-scale 2^5
#define E8M0S  0x7A7A7A7Au      // 122 -> 2^-5 in every byte (both operands)

typedef int    v4i    __attribute__((ext_vector_type(4)));
typedef int    v8i    __attribute__((ext_vector_type(8)));
typedef float  f32x16 __attribute__((ext_vector_type(16)));

__device__ __forceinline__ void glds16(const void* g, void* l) {
    __builtin_amdgcn_global_load_lds(
        (const __attribute__((address_space(1))) void*)g,
        (__attribute__((address_space(3))) void*)l,
        16, 0, 0);
}

__device__ __forceinline__ float fexp2(float x) {
#if __has_builtin(__builtin_amdgcn_exp2f)
    return __builtin_amdgcn_exp2f(x);
#else
    return exp2f(x);
#endif
}
__device__ __forceinline__ float flog2(float x) {
#if __has_builtin(__builtin_amdgcn_logf)
    return __builtin_amdgcn_logf(x);
#else
    return log2f(x);
#endif
}

// fp4 e2m1 round-to-nearest encode of y (|y| clipped to 6).
__device__ __forceinline__ unsigned fp4_nib(float y) {
    unsigned s = (__float_as_uint(y) >> 31) << 3;
    float a = fminf(fabsf(y), 6.0f);
    unsigned c = (unsigned)(a >= 0.25f) + (unsigned)(a >= 0.75f) +
                 (unsigned)(a >= 1.25f) + (unsigned)(a >= 1.75f) +
                 (unsigned)(a >= 2.5f)  + (unsigned)(a >= 3.5f)  +
                 (unsigned)(a >= 5.0f);
    return c | s;
}

// Wave-per-row, grid-stride. Lane-interleaved float4 loads: every load
// instruction is a fully-coalesced 1KB wave transaction.
__global__ __launch_bounds__(256) void norm_fused(
    const float* __restrict__ img,
    const float* __restrict__ txt,
    unsigned char* __restrict__ imgQ,   // [NROWS][512] packed fp4
    unsigned char* __restrict__ txtQ,
    const float* __restrict__ lscale,
    const float* __restrict__ lbias,
    float* __restrict__ diagPart) {
    const int t    = threadIdx.x;
    const int lane = t & 63;
    const int wave = t >> 6;
    const int gw   = blockIdx.x * 4 + wave;   // 8192 waves total
    const float sc   = __expf(lscale[0]);
    const float bias = lbias[0];

    for (int row = gw; row < NROWS; row += 8192) {
        const float4* pi = (const float4*)(img + (size_t)row * DIM);
        const float4* pt = (const float4*)(txt + (size_t)row * DIM);
        float4 vi[4], vt[4];
        float ssi = 0.0f, sst = 0.0f, dot = 0.0f;
        #pragma unroll
        for (int j = 0; j < 4; ++j) {
            vi[j] = pi[lane + 64 * j];
            vt[j] = pt[lane + 64 * j];
            ssi += vi[j].x*vi[j].x + vi[j].y*vi[j].y + vi[j].z*vi[j].z + vi[j].w*vi[j].w;
            sst += vt[j].x*vt[j].x + vt[j].y*vt[j].y + vt[j].z*vt[j].z + vt[j].w*vt[j].w;
            dot += vi[j].x*vt[j].x + vi[j].y*vt[j].y + vi[j].z*vt[j].z + vi[j].w*vt[j].w;
        }
        #pragma unroll
        for (int off = 1; off < 64; off <<= 1) {
            ssi += __shfl_xor(ssi, off, 64);
            sst += __shfl_xor(sst, off, 64);
            dot += __shfl_xor(dot, off, 64);
        }
        const float ii = 1.0f / fmaxf(sqrtf(ssi), 1e-12f);
        const float it = 1.0f / fmaxf(sqrtf(sst), 1e-12f);
        if (lane == 0) diagPart[row] = -fmaf(sc, dot * ii * it, bias);

        const float qi = ii * QSCALE, qt = it * QSCALE;
        ushort* oi = (ushort*)(imgQ + (size_t)row * 512);
        ushort* ot = (ushort*)(txtQ + (size_t)row * 512);
        #pragma unroll
        for (int j = 0; j < 4; ++j) {
            unsigned p = fp4_nib(vi[j].x * qi)        | (fp4_nib(vi[j].y * qi) << 4) |
                         (fp4_nib(vi[j].z * qi) << 8) | (fp4_nib(vi[j].w * qi) << 12);
            unsigned q = fp4_nib(vt[j].x * qt)        | (fp4_nib(vt[j].y * qt) << 4) |
                         (fp4_nib(vt[j].z * qt) << 8) | (fp4_nib(vt[j].w * qt) << 12);
            oi[lane + 64 * j] = (ushort)p;
            ot[lane + 64 * j] = (ushort)q;
        }
    }
}

// MX-fp4 GEMM, R8: MANY SMALL INDEPENDENT BLOCKS (m97/m114 structure).
// R2-R7 (all 512-thr monolith variants) were schedule-invariant at
// ~190us / 32% MfmaUtil: register-pinned 2 waves/SIMD + block-wide
// barriers phase-lock both SIMD-resident waves -> LDS-read phase and
// MFMA phase serialize (sum, not max). Fix is structural, not schedule:
// 256-thr blocks (4 waves as 2x2 of 64x64 wave tiles; acc=64 AGPR),
// 128x128 block tile, 32KB single-buffer LDS, __launch_bounds__(256,4)
// -> 4 INDEPENDENT blocks/CU (16 waves/CU). Blocks share no barriers;
// phase drift lets block X's stage/read stalls hide under block Y/Z/W's
// MFMA (m114: co-resident waves overlap at max, not sum).
// K-loop uses plain LDS reads + __syncthreads(); compiler inserts
// fine-grained counted lgkmcnt (m97 behavior). setprio kept: m191 shows
// it pays exactly in the independent-small-block regime.
// Proven pieces unchanged: zero-conflict scatter swizzle (LDS slot s of
// row r holds global chunk s ^ (r&7) ^ ((r>>4)&1); read xr formula
// invariant to the new tile since offsets are multiples of 32),
// T1 XCD banding, softplus epilogue + diag fix.
__global__ __launch_bounds__(256, 4) void siglip_gemm(
    const unsigned char* __restrict__ A,
    const unsigned char* __restrict__ B,
    const float* __restrict__ lscale,
    const float* __restrict__ lbias,
    float* __restrict__ gemmPart)
{
    __shared__ unsigned char sA[128 * 128];  // 16 KB
    __shared__ unsigned char sB[128 * 128];  // 16 KB
    __shared__ float wred[4];

    const int t    = threadIdx.x;
    const int lane = t & 63;
    const int wave = t >> 6;        // 0..3
    const int wr   = wave >> 1;     // 0..1 : A half (64 rows)
    const int wc   = wave & 1;      // 0..1 : B half (64 cols)
    const int r31  = lane & 31;
    const int h    = lane >> 5;     // k-half (32-elem MX block)
    const int xr   = (r31 & 7) ^ ((r31 >> 4) & 1);  // scatter row swizzle

    // T1 XCD-bijective map: 16384 blocks = 8 xcd x 2048 lb.
    // Each XCD owns a 16-bcol B band (2048 rows x 512B = 1MB, L2-resident);
    // consecutive lb share brow -> A panel L2-reused 16x.
    const int b    = blockIdx.x;
    const int xcd  = b & 7;
    const int lb   = b >> 3;               // 0..2047
    const int bcol = xcd * 16 + (lb & 15); // 0..127
    const int brow = lb >> 4;              // 0..127

    const size_t aBase = (size_t)brow * 128;
    const size_t bBase = (size_t)bcol * 128;

    // Staging: glds16 = 1KB = 8 rows x 128B. lane -> (srow=l>>3, slot=l&7).
    // Wave w stages A rows [w*32, w*32+32) = 4 slabs; same for B. (128 rows
    // total, 4 waves x 32.)
    const int srow = lane >> 3;
    const int c0   = (lane & 7) ^ srow;
    const int d01  = (c0 & 1) ? -16 : 16;   // toggle chunk bit0 when (row>>4)&1

    const unsigned char* aP = A + (size_t)(aBase + wave * 32 + srow) * 512 + c0 * 16;
    const unsigned char* bP = B + (size_t)(bBase + wave * 32 + srow) * 512 + c0 * 16;
    char* la  = ((char*)sA) + wave * 4096;
    char* lbp = ((char*)sB) + wave * 4096;

    int rbA[2], rbB[2];
    #pragma unroll
    for (int i = 0; i < 2; ++i) rbA[i] = (wr * 64 + i * 32 + r31) * 128;
    #pragma unroll
    for (int i = 0; i < 2; ++i) rbB[i] = (wc * 64 + i * 32 + r31) * 128;

    f32x16 acc[2][2] = {};

    // ---- prologue: stage K-tile 0 ----
    #pragma unroll
    for (int j = 0; j < 4; ++j) {
        const int tog = ((j >> 1) & 1) ? d01 : 0;   // bit4 of row = (j>>1)&1
        glds16(aP + j * 4096 + tog, la + j * 1024);
        glds16(bP + j * 4096 + tog, lbp + j * 1024);
    }
    __syncthreads();   // compiler emits vmcnt(0) drain + barrier

    #pragma unroll
    for (int k = 0; k < 4; ++k) {
        // ---- compute K-tile k: 4 slices, compiler-scheduled waits ----
        #pragma unroll
        for (int ks = 0; ks < 4; ++ks) {
            const int s = ((ks * 2 + h) ^ xr) * 16;
            v4i a0 = *(const v4i*)(sA + rbA[0] + s);
            v4i a1 = *(const v4i*)(sA + rbA[1] + s);
            v4i b0 = *(const v4i*)(sB + rbB[0] + s);
            v4i b1 = *(const v4i*)(sB + rbB[1] + s);
            v8i A0 = __builtin_shufflevector(a0, a0, 0, 1, 2, 3, -1, -1, -1, -1);
            v8i A1 = __builtin_shufflevector(a1, a1, 0, 1, 2, 3, -1, -1, -1, -1);
            v8i B0 = __builtin_shufflevector(b0, b0, 0, 1, 2, 3, -1, -1, -1, -1);
            v8i B1 = __builtin_shufflevector(b1, b1, 0, 1, 2, 3, -1, -1, -1, -1);
            __builtin_amdgcn_s_setprio(1);
            acc[0][0] = __builtin_amdgcn_mfma_scale_f32_32x32x64_f8f6f4(
                A0, B0, acc[0][0], 4, 4, 0, (int)E8M0S, 0, (int)E8M0S);
            acc[0][1] = __builtin_amdgcn_mfma_scale_f32_32x32x64_f8f6f4(
                A0, B1, acc[0][1], 4, 4, 0, (int)E8M0S, 0, (int)E8M0S);
            acc[1][0] = __builtin_amdgcn_mfma_scale_f32_32x32x64_f8f6f4(
                A1, B0, acc[1][0], 4, 4, 0, (int)E8M0S, 0, (int)E8M0S);
            acc[1][1] = __builtin_amdgcn_mfma_scale_f32_32x32x64_f8f6f4(
                A1, B1, acc[1][1], 4, 4, 0, (int)E8M0S, 0, (int)E8M0S);
            __builtin_amdgcn_s_setprio(0);
        }

        // ---- stage K-tile k+1 (single buffer: reads must drain first) ----
        if (k < 3) {
            __syncthreads();                 // all waves' reads retired
            const unsigned char* aN = aP + (k + 1) * 128;
            const unsigned char* bN = bP + (k + 1) * 128;
            #pragma unroll
            for (int j = 0; j < 4; ++j) {
                const int tog = ((j >> 1) & 1) ? d01 : 0;
                glds16(aN + j * 4096 + tog, la + j * 1024);
                glds16(bN + j * 4096 + tog, lbp + j * 1024);
            }
            __syncthreads();                 // vmcnt(0) drain + visibility
        }
    }

    // Epilogue: softplus(z) over all elements (label=-1 form); diagonal fixed
    // by -z_ii (diagPart). Group-of-4 log trick (4-term product < 2^125: safe).
    const float l2e   = 1.44269504088896341f;
    const float scale = __expf(lscale[0]);
    const float aCo   = scale * l2e;
    const float bCo   = lbias[0] * l2e;
    float local = 0.0f;
    #pragma unroll
    for (int mi = 0; mi < 2; ++mi)
        #pragma unroll
        for (int ni = 0; ni < 2; ++ni)
            #pragma unroll
            for (int r = 0; r < 16; r += 4) {
                float e0 = fexp2(fmaf(aCo, acc[mi][ni][r + 0], bCo));
                float e1 = fexp2(fmaf(aCo, acc[mi][ni][r + 1], bCo));
                float e2 = fexp2(fmaf(aCo, acc[mi][ni][r + 2], bCo));
                float e3 = fexp2(fmaf(aCo, acc[mi][ni][r + 3], bCo));
                float p  = ((1.0f + e0) * (1.0f + e1)) *
                           ((1.0f + e2) * (1.0f + e3));
                local += flog2(p);
            }

    #pragma unroll
    for (int off = 32; off > 0; off >>= 1) local += __shfl_down(local, off, 64);
    if (lane == 0) wred[wave] = local;
    __syncthreads();
    if (t == 0)
        gemmPart[blockIdx.x] =
            (wred[0] + wred[1] + wred[2] + wred[3]) * 0.69314718055994531f;
}

// Sum 32768 partials (diagPart 16384 ++ gemmPart 16384, contiguous) -> loss.
__global__ __launch_bounds__(1024) void finalize_kernel(
    const float* __restrict__ parts, float* __restrict__ out) {
    __shared__ float wr[16];
    const int t    = threadIdx.x;
    const int lane = t & 63;
    const int wave = t >> 6;
    const float4* p4 = (const float4*)parts;   // 8192 float4
    float s = 0.0f;
    for (int i = t; i < 8192; i += 1024) {
        float4 v = p4[i];
        s += v.x + v.y + v.z + v.w;
    }
    #pragma unroll
    for (int off = 32; off > 0; off >>= 1) s += __shfl_down(s, off, 64);
    if (lane == 0) wr[wave] = s;
    __syncthreads();
    if (t == 0) {
        float tot = 0.0f;
        #pragma unroll
        for (int i = 0; i < 16; ++i) tot += wr[i];
        out[0] = tot / 268435456.0f;   // / N^2
    }
}

extern "C" void kernel_launch(void* const* d_in, const int* in_sizes, int n_in,
                              void* d_out, int out_size, void* d_ws, size_t ws_size,
                              hipStream_t stream) {
    const float* img    = (const float*)d_in[0];
    const float* txt    = (const float*)d_in[1];
    const float* lscale = (const float*)d_in[2];
    const float* lbias  = (const float*)d_in[3];
    float* out = (float*)d_out;

    char* ws = (char*)d_ws;
    unsigned char* imgQ = (unsigned char*)ws;                          // 8 MB
    unsigned char* txtQ = (unsigned char*)(ws + (size_t)NROWS * 512);  // 8 MB
    float* parts   = (float*)(ws + (size_t)2 * NROWS * 512);           // 32768 floats
    float* diagPart = parts;
    float* gemmPart = parts + NROWS;

    norm_fused<<<2048, 256, 0, stream>>>(img, txt, imgQ, txtQ, lscale, lbias, diagPart);
    siglip_gemm<<<dim3((NROWS / 128) * (NROWS / 128)), 256, 0, stream>>>(
        imgQ, txtQ, lscale, lbias, gemmPart);
    finalize_kernel<<<1, 1024, 0, stream>>>(parts, out);
}